// Round 7
// baseline (52.641 us; speedup 1.0000x reference)
//
#include <hip/hip_runtime.h>
#include <math.h>

// AntiAliasInterpolation2d: depthwise 13x13 gaussian blur + 4x nearest downsample,
// fused so only the 128x128 sampled output rows/cols are ever computed.
//
// x: (8, 512, 512, 32) f32 NHWC.  out: (8, 128, 128, 32) f32.
// Separable: out(r,c) = sum_i w[i] * sum_j w[j] * x(4r+i-6, 4c+j-6), zero-padded.
//
// R7 changes vs R6 (52.4us; latency-bound diagnosis: only 2 waves/SIMD and
// 1-row lookahead leaves the load->write->read chain exposed):
//  - 2-ROW LOOKAHEAD: wave-private TRIPLE-buffered LDS; loads for row s+2
//    issued at step s into register staging (svA/svB, statically named per
//    rule #20; compiler emits counted vmcnt from register deps - never 0).
//  - Exact 41-px staging (was 48): 5 full wave-loads + 1 broadcast-line tail
//    (branch-free; pad slots p=41..47 get unread duplicates). -15% VMEM lines.
//  - Geometry unchanged: 512 blocks (2/CU), 4 waves x (8 col x 8 row) tiles,
//    serpentine sweep, XCD swizzle, XOR bank swizzle, no main-loop barriers.

#define HH 512
#define WW 512
#define CC 32
#define OH 128
#define OW 128
#define KS 13
#define KA 6
#define TR 8               // output rows per wave
#define TCW 8              // output cols per wave
#define NROWS (4*TR + 9)   // 41 input row-steps
#define NPXW 41            // needed pixels per wave-row (4*TCW+9)
#define SLOTS (48*8)       // 384 float4 slots per buffer (48-px layout kept)

struct W13 { float w[KS]; };

__device__ __forceinline__ int swz(int p, int c) {
    return p * 8 + (c ^ ((p >> 2) & 7));   // float4-slot index in a row buffer
}

__global__ __launch_bounds__(256, 2)
void aa_blur_down_kernel(const float* __restrict__ x, float* __restrict__ out, W13 wk)
{
    __shared__ float4 lbuf[4][3][SLOTS];   // per-wave TRIPLE buffers (72 KB)
    __shared__ float WV[NROWS][TR];        // vertical weights (shared, read-only)

    const int tid  = threadIdx.x;
    const int wid  = tid >> 6;
    const int lane = tid & 63;

    // XCD-aware bijective swizzle: 512 blocks = 8 XCDs x 64. Consecutive lids
    // are rt-neighbors on the same XCD (phase-aligned halo -> L2 hits).
    int bid = blockIdx.x;
    int lid = (bid & 7) * 64 + (bid >> 3);
    int rt  = lid & 15;          // row tile   (16)
    int ctb = (lid >> 4) & 3;    // col block  (4)  -> 4 waves = 32 cols
    int n   = lid >> 6;          // batch      (8)

    const int r0 = rt * TR;
    const int y0 = 4 * r0 - KA;  // input row of local row-step 0

    // Vertical-weight table; row validity (zero padding) folded into the weight.
    for (int idx = tid; idx < NROWS * TR; idx += 256) {
        int yl = idx >> 3;
        int r  = idx & (TR - 1);
        int i  = yl - 4 * r;
        int y  = y0 + yl;
        bool ok = (i >= 0) && (i < KS) && ((unsigned)y < (unsigned)HH);
        WV[yl][r] = ok ? wk.w[i < 0 ? 0 : (i >= KS ? KS - 1 : i)] : 0.0f;
    }
    __syncthreads();             // the ONLY barrier

    const int ch4 = lane & 7;    // float4 group of the 32 channels
    const int cwL = lane >> 3;   // 0..7 col worker within the wave
    const int cw0 = (ctb * 4 + wid) * TCW;  // wave's first output col
    const int c   = cw0 + cwL;
    const int cb  = 4 * cw0 - KA;           // input col of wave-local px 0
    const int psub = lane >> 3;  // staging pixel sub-index

    const float* xn = x + (size_t)n * HH * WW * CC;

    float4 acc[TR];
#pragma unroll
    for (int r = 0; r < TR; ++r) acc[r] = make_float4(0.f, 0.f, 0.f, 0.f);

    // Serpentine: even rt sweeps top->bottom, odd rt bottom->top, so halo rows
    // shared with the vertical neighbor are touched at the same sweep phase.
    const bool up  = (rt & 1);
    const int  ylS = up ? (NROWS - 1) : 0;
    const int  dir = up ? -1 : 1;

    // ---- wave-private staging: 5 full wave-loads (40 px) + 1 broadcast tail ----
#define LOADROW(SV, YL)                                                             \
    {                                                                               \
        int y  = y0 + (YL);                                                         \
        int yc = y < 0 ? 0 : (y >= HH ? HH - 1 : y);                                \
        const float* rowp = xn + (size_t)yc * (WW * CC);                            \
        _Pragma("unroll")                                                           \
        for (int it = 0; it < 5; ++it) {                                            \
            int p  = it * 8 + psub;                                                 \
            int gx = cb + p;                                                        \
            bool ok = (unsigned)gx < (unsigned)WW;                                  \
            int gxc = gx < 0 ? 0 : (gx >= WW ? WW - 1 : gx);                        \
            float4 v = *reinterpret_cast<const float4*>(rowp + (size_t)gxc * CC + ch4 * 4); \
            SV[it] = ok ? v : make_float4(0.f, 0.f, 0.f, 0.f);                      \
        }                                                                           \
        {   /* tail px 40: all lanes load the same 128B line (1 line of traffic) */ \
            int gx = cb + 40;                                                       \
            bool ok = (unsigned)gx < (unsigned)WW;                                  \
            int gxc = gx >= WW ? WW - 1 : gx;                                       \
            float4 v = *reinterpret_cast<const float4*>(rowp + (size_t)gxc * CC + ch4 * 4); \
            SV[5] = ok ? v : make_float4(0.f, 0.f, 0.f, 0.f);                       \
        }                                                                           \
    }

#define WRITEROW(B, SV)                                                             \
    {                                                                               \
        _Pragma("unroll")                                                           \
        for (int it = 0; it < 6; ++it) {                                            \
            int p = it * 8 + psub;   /* it=5 -> slots 40..47; 41..47 never read */  \
            lbuf[wid][B][swz(p, ch4)] = SV[it];                                     \
        }                                                                           \
    }

    // One pipeline step: compute logical row-step S from buffer rbuf; issue
    // loads for S+2 into SVL; write SVW (data for S+1) into wbuf.
#define STEP(S, SVL, SVW)                                                           \
    {                                                                               \
        const int s_ = (S);                                                         \
        if (s_ + 2 < NROWS) LOADROW(SVL, ylS + dir * (s_ + 2));                     \
        const int yl = ylS + dir * s_;                                              \
        float4 h = make_float4(0.f, 0.f, 0.f, 0.f);                                 \
        _Pragma("unroll")                                                           \
        for (int j = 0; j < KS; ++j) {                                              \
            float4 v = lbuf[wid][rbuf][swz(4 * cwL + j, ch4)];                      \
            float wj = wk.w[j];                                                     \
            h.x = fmaf(wj, v.x, h.x);                                               \
            h.y = fmaf(wj, v.y, h.y);                                               \
            h.z = fmaf(wj, v.z, h.z);                                               \
            h.w = fmaf(wj, v.w, h.w);                                               \
        }                                                                           \
        _Pragma("unroll")                                                           \
        for (int r = 0; r < TR; ++r) {                                              \
            float wv = WV[yl][r];                                                   \
            acc[r].x = fmaf(wv, h.x, acc[r].x);                                     \
            acc[r].y = fmaf(wv, h.y, acc[r].y);                                     \
            acc[r].z = fmaf(wv, h.z, acc[r].z);                                     \
            acc[r].w = fmaf(wv, h.w, acc[r].w);                                     \
        }                                                                           \
        if (s_ + 1 < NROWS) WRITEROW(wbuf, SVW);                                    \
        rbuf = (rbuf == 2) ? 0 : rbuf + 1;                                          \
        wbuf = (wbuf == 2) ? 0 : wbuf + 1;                                          \
    }

    float4 svA[6], svB[6];
    // prologue: rows 0 and 1 in flight; row 0 written to buffer 0
    LOADROW(svA, ylS);
    LOADROW(svB, ylS + dir);
    WRITEROW(0, svA);
    int rbuf = 0, wbuf = 1;

    int s = 0;
    for (; s + 1 < NROWS; s += 2) {   // pairs keep svA/svB statically named
        STEP(s,     svA, svB);
        STEP(s + 1, svB, svA);
    }
    if (s < NROWS) STEP(s, svA, svB); // NROWS=41 -> final odd step

#pragma unroll
    for (int r = 0; r < TR; ++r) {
        float* o = out + (((size_t)n * OH + (r0 + r)) * OW + c) * CC + ch4 * 4;
        *reinterpret_cast<float4*>(o) = acc[r];
    }
}

extern "C" void kernel_launch(void* const* d_in, const int* in_sizes, int n_in,
                              void* d_out, int out_size, void* d_ws, size_t ws_size,
                              hipStream_t stream)
{
    const float* x = (const float*)d_in[0];
    float* out = (float*)d_out;

    // Rebuild the separable gaussian weights on the host (double precision).
    // Reference: g[i]=exp(-(i-6)^2/(2*1.5^2)); w[i]=g[i]/sum(g); k2=outer(w,w).
    W13 wk;
    double g[KS], s = 0.0;
    for (int i = 0; i < KS; ++i) {
        double d = i - (KS - 1) / 2.0;
        g[i] = exp(-(d * d) / (2.0 * 1.5 * 1.5));
        s += g[i];
    }
    for (int i = 0; i < KS; ++i) wk.w[i] = (float)(g[i] / s);

    dim3 grid(8 * 4 * 16);   // batch x col-blocks x row-tiles = 512 blocks
    aa_blur_down_kernel<<<grid, 256, 0, stream>>>(x, out, wk);
}